// Round 19
// baseline (2122.483 us; speedup 1.0000x reference)
//
#include <hip/hip_runtime.h>

// R17: issue-early/consume-late restructure of R16 (1.05ms).
// Diagnosis: phases ~11k cyc vs ~4.5k overlap-floor; gap = L2-latency
// serialization (streamed frags loaded 2-deep right before use). Fix (T14):
//  - Encoder phase: ALL streamed eWhh1 frags issued at phase top ->
//    L0 computed FIRST (LDS/persistent only, ~2k cyc of cover) -> L1
//    consumes landed frags. L0/L1 independent given h0r (both read h0r,
//    L0 writes h0w) -> order swap is math-identical.
//  - Decoder B: dWhh1 groups loaded at top, persistent-pwi MFMAs cover.
//  - Decoder A: Wcomb groups at top, FC + wL/pb3 MFMAs cover.
// Register demand ~216 (<256): pwi 64 + pb3 16 + in-flight 32 + wx0 16
// + acc 32 + c 16 + misc. Everything else identical to R16.

using s16x8 = __attribute__((ext_vector_type(8))) short;
using h16x8 = __attribute__((ext_vector_type(8))) _Float16;
using f32x4 = __attribute__((ext_vector_type(4))) float;

#define DEV static __device__ __forceinline__

DEV unsigned short f2h(float f) {
  _Float16 h = (_Float16)f;  // RNE
  return __builtin_bit_cast(unsigned short, h);
}
DEV float h2f(short h) {
  return (float)__builtin_bit_cast(_Float16, (unsigned short)h);
}
DEV float rcp_(float x) { return __builtin_amdgcn_rcpf(x); }
DEV float sigm(float v) { return rcp_(1.0f + __expf(-v)); }
DEV float tanh_(float v) {  // 1 - 2/(e^{2v}+1)
  float e = __expf(2.0f * v);
  return 1.0f - 2.0f * rcp_(e + 1.0f);
}
DEV f32x4 mf(s16x8 a, s16x8 b, f32x4 c) {
  return __builtin_amdgcn_mfma_f32_16x16x32_f16(
      __builtin_bit_cast(h16x8, a), __builtin_bit_cast(h16x8, b), c, 0, 0, 0);
}
DEV f32x4 splat4(float v) { f32x4 r = {v, v, v, v}; return r; }

// [rows][128] fp16 buffer; 16 slots of 8 fp16 per row, XOR-swizzled.
DEV int swz(int row, int slot) { return row * 256 + (((slot ^ row) & 15) << 4); }
DEV s16x8 ldA(const char* buf, int rt, int ks, int lo, int hi) {
  return *(const s16x8*)(buf + swz(rt * 16 + lo, ks * 4 + hi));
}
DEV s16x8 ldB(const char* wlds, int colbase, int ks, int lo, int hi) {
  return *(const s16x8*)(wlds + swz(colbase + lo, ks * 4 + hi));
}
DEV void storeH(char* buf, int row, int col, unsigned short v) {
  int addr = row * 256 + ((((col >> 3) ^ row) & 15) << 4) + (col & 7) * 2;
  *(unsigned short*)(buf + addr) = v;
}
DEV unsigned short cellup(float gi, float gf, float gg, float go, float& c) {
  float i = sigm(gi), f = sigm(gf), g2 = tanh_(gg), o = sigm(go);
  c = f * c + i * g2;
  return f2h(o * tanh_(c));
}

// ---- d_ws layout (bytes) ----
// frag records, mats m*131072, addr = m*131072 + ks*32768 + col*64 + hi*16
//   m: 0=eWih1 1=eWhh1 2=dWih1 3=dWhh1 4=eWhh0 5=dWhh0 6=Wcomb(dWih0@fcW)
// WX (eWih0 K=16 zero-pad-32 frags) @917504 (32KB)
// IMG_E (eWhh0 rows 0..383 swizzled) @950272 (96KB)
// IMG_D (dWhh0 rows 0..383 swizzled) @1048576 (96KB)
#define WS_WX  917504
#define WS_IME 950272
#define WS_IMD 1048576

__global__ void prep_kernel(
    const float* __restrict__ eWih0, const float* __restrict__ eWhh0,
    const float* __restrict__ eWih1, const float* __restrict__ eWhh1,
    const float* __restrict__ dWih0, const float* __restrict__ dWhh0,
    const float* __restrict__ dWih1, const float* __restrict__ dWhh1,
    const float* __restrict__ fcW, char* __restrict__ ws) {
  int idx = blockIdx.x * 256 + threadIdx.x;
  if (idx < 57344) {  // 7 mats x 8192 fragment records
    int m = idx >> 13, r = idx & 8191;
    int col = r >> 4, ks = (r >> 2) & 3, hi = r & 3;
    s16x8 v;
    if (m == 6) {  // Wcomb[col][k] = dWih0[col][0]*fcW[0][k]+dWih0[col][1]*fcW[1][k]
      float w0 = dWih0[col * 2 + 0], w1 = dWih0[col * 2 + 1];
#pragma unroll
      for (int j = 0; j < 8; ++j) {
        int k = ks * 32 + hi * 8 + j;
        v[j] = (short)f2h(w0 * fcW[k] + w1 * fcW[128 + k]);
      }
    } else {
      const float* W;
      switch (m) {
        case 0: W = eWih1; break;
        case 1: W = eWhh1; break;
        case 2: W = dWih1; break;
        case 3: W = dWhh1; break;
        case 4: W = eWhh0; break;
        default: W = dWhh0; break;
      }
      const float* p = W + col * 128 + ks * 32 + hi * 8;
#pragma unroll
      for (int j = 0; j < 8; ++j) v[j] = (short)f2h(p[j]);
    }
    *(s16x8*)(ws + m * 131072 + ks * 32768 + col * 64 + hi * 16) = v;
  } else if (idx < 59392) {  // WX frags
    int r3 = idx - 57344;
    int col = r3 >> 2, hi = r3 & 3;
    s16x8 v;
#pragma unroll
    for (int j = 0; j < 8; ++j) v[j] = 0;
    if (hi < 2) {
      const float* p = eWih0 + col * 16 + hi * 8;
#pragma unroll
      for (int j = 0; j < 8; ++j) v[j] = (short)f2h(p[j]);
    }
    *(s16x8*)(ws + WS_WX + col * 64 + hi * 16) = v;
  } else if (idx < 71680) {  // swizzled 3-gate images (rows 0..383)
    int r2 = idx - 59392;
    int m = (r2 >= 6144), rr = m ? r2 - 6144 : r2;
    int row = rr >> 4, s = rr & 15;
    const float* p = (m ? dWhh0 : eWhh0) + row * 128 + s * 8;
    s16x8 v;
#pragma unroll
    for (int j = 0; j < 8; ++j) v[j] = (short)f2h(p[j]);
    *(s16x8*)(ws + (m ? WS_IMD : WS_IME) + row * 256 + (((s ^ row) & 15) << 4)) = v;
  }
}

__global__ __launch_bounds__(512, 2) void fused_kernel(
    const float* __restrict__ x,
    const float* __restrict__ ebih0, const float* __restrict__ ebhh0,
    const float* __restrict__ ebih1, const float* __restrict__ ebhh1,
    const float* __restrict__ dWih0,
    const float* __restrict__ dbih0, const float* __restrict__ dbhh0,
    const float* __restrict__ dbih1, const float* __restrict__ dbhh1,
    const float* __restrict__ fcW, const float* __restrict__ fcb,
    const char* __restrict__ ws, float* __restrict__ out) {
  __shared__ __align__(16) char smem[136960];
  char* wL   = smem;                       // 98304: 3-gate W_hh0 image
  char* h0B  = smem + 98304;               // 2 x 8192
  char* h1B  = smem + 114688;              // 2 x 8192
  char* xB   = smem + 131072;              // 2 x 2560
  float* inpL = (float*)(smem + 136192);   // 32x2 fp32 (decoder t=0 input)
  char* fcwL = smem + 136448;              // 2x128 fp16

  const int tid = threadIdx.x;
  const int w = tid >> 6, l = tid & 63, lo = l & 15, hi = l >> 4;
  const int row0 = blockIdx.x * 32;
  const int colb = w * 16;
  const int obase = (colb + lo) * 64 + hi * 16;   // frag offset, gate 0
  const int obase3 = obase + 384 * 64;            // gate 3

  // ================= init =================
  {  // stage IMG_E -> wL
    const int4* src = (const int4*)(ws + WS_IME);
    int4* dst = (int4*)wL;
    for (int i = tid; i < 6144; i += 512) dst[i] = src[i];
  }
  {  // zero h0B,h1B,xB
    int4 z = make_int4(0, 0, 0, 0);
    int4* p = (int4*)h0B;
    for (int i = tid; i < 2368; i += 512) p[i] = z;
  }

  float b0[4], b1[4];
  s16x8 wx0[4];
#pragma unroll
  for (int g = 0; g < 4; ++g) {
    int col = g * 128 + colb + lo;
    b0[g] = ebih0[col] + ebhh0[col];
    b1[g] = ebih1[col] + ebhh1[col];
    wx0[g] = *(const s16x8*)(ws + WS_WX + g * 8192 + obase);
  }
  // persistent weight fragments (loaded ONCE; reloaded at decoder switch)
  s16x8 pwi[4][4], pb3[4];
#pragma unroll
  for (int ks = 0; ks < 4; ++ks) {
#pragma unroll
    for (int g = 0; g < 4; ++g)
      pwi[ks][g] = *(const s16x8*)(ws + /*eWih1*/ ks * 32768 + g * 8192 + obase);
    pb3[ks] = *(const s16x8*)(ws + 4 * 131072 + ks * 32768 + obase3);  // eWhh0 g3
  }

  float c0s[2][4], c1s[2][4];
#pragma unroll
  for (int rt = 0; rt < 2; ++rt)
#pragma unroll
    for (int r = 0; r < 4; ++r) { c0s[rt][r] = 0.f; c1s[rt][r] = 0.f; }

  const int xr = tid >> 4, xf = tid & 15;
  const float* xrow = x + (long long)(row0 + xr) * 1600 + xf;
  *(unsigned short*)(xB + xr * 80 + xf * 2) = f2h(xrow[0]);  // x_0
  float xv = xrow[16];  // x_1
  int cur = 0;
  __syncthreads();

  // ================= encoder: 101 fused phases, 1 barrier each ============
  for (int k = 0; k <= 100; ++k) {
    char* h0r = h0B + cur * 8192;
    char* h0w = h0B + (cur ^ 1) * 8192;
    char* h1r = h1B + cur * 8192;
    char* h1w = h1B + (cur ^ 1) * 8192;
    char* xc  = xB + cur * 2560;
    char* xn  = xB + (cur ^ 1) * 2560;

    float xv_stage = xv;                       // x_{k+1}
    if (k < 98) xv = xrow[(k + 2) * 16];       // issue prefetch early

    // ---- issue ALL streamed eWhh1 frags at phase top (land under L0)
    s16x8 sf[4][4];
    if (k > 0) {
      int lf = 0;
      asm("" : "+s"(lf));  // defeat LICM
      const char* W1h = ws + 131072 + lf;  // eWhh1 records
#pragma unroll
      for (int ks = 0; ks < 4; ++ks)
#pragma unroll
        for (int g = 0; g < 4; ++g)
          sf[ks][g] = *(const s16x8*)(W1h + ks * 32768 + g * 8192 + obase);
    }

    if (k < 100) {  // ---- layer 0 FIRST (LDS/persistent only): h0(k+1)
      f32x4 acc[2][4];
#pragma unroll
      for (int g = 0; g < 4; ++g) { acc[0][g] = splat4(b0[g]); acc[1][g] = splat4(b0[g]); }
      {
        s16x8 a0 = *(const s16x8*)(xc + lo * 80 + hi * 16);
        s16x8 a1 = *(const s16x8*)(xc + (16 + lo) * 80 + hi * 16);
#pragma unroll
        for (int g = 0; g < 4; ++g) {
          acc[0][g] = mf(a0, wx0[g], acc[0][g]);
          acc[1][g] = mf(a1, wx0[g], acc[1][g]);
        }
      }
#pragma unroll
      for (int ks = 0; ks < 4; ++ks) {
        s16x8 a0 = ldA(h0r, 0, ks, lo, hi), a1 = ldA(h0r, 1, ks, lo, hi);
#pragma unroll
        for (int g = 0; g < 3; ++g) {
          s16x8 bb = ldB(wL, g * 128 + colb, ks, lo, hi);
          acc[0][g] = mf(a0, bb, acc[0][g]);
          acc[1][g] = mf(a1, bb, acc[1][g]);
        }
        acc[0][3] = mf(a0, pb3[ks], acc[0][3]);
        acc[1][3] = mf(a1, pb3[ks], acc[1][3]);
      }
#pragma unroll
      for (int rt = 0; rt < 2; ++rt)
#pragma unroll
        for (int r = 0; r < 4; ++r)
          storeH(h0w, rt * 16 + hi * 4 + r, colb + lo,
                 cellup(acc[rt][0][r], acc[rt][1][r], acc[rt][2][r], acc[rt][3][r], c0s[rt][r]));
      if (k < 99)  // stage x_{k+1} for next phase
        *(unsigned short*)(xn + xr * 80 + xf * 2) = f2h(xv_stage);
    }

    if (k > 0) {  // ---- layer 1: h1(k) = cell1(h0(k)@eWih1 + h1(k-1)@eWhh1)
      f32x4 acc[2][4];
#pragma unroll
      for (int g = 0; g < 4; ++g) { acc[0][g] = splat4(b1[g]); acc[1][g] = splat4(b1[g]); }
      // persistent half: A = h0(k) (h0r), B = pwi (eWih1)
#pragma unroll
      for (int ks = 0; ks < 4; ++ks) {
        s16x8 a0 = ldA(h0r, 0, ks, lo, hi), a1 = ldA(h0r, 1, ks, lo, hi);
#pragma unroll
        for (int g = 0; g < 4; ++g) {
          acc[0][g] = mf(a0, pwi[ks][g], acc[0][g]);
          acc[1][g] = mf(a1, pwi[ks][g], acc[1][g]);
        }
      }
      // streamed half: A = h1(k-1), B = sf (landed during L0)
#pragma unroll
      for (int ks = 0; ks < 4; ++ks) {
        s16x8 a0 = ldA(h1r, 0, ks, lo, hi), a1 = ldA(h1r, 1, ks, lo, hi);
#pragma unroll
        for (int g = 0; g < 4; ++g) {
          acc[0][g] = mf(a0, sf[ks][g], acc[0][g]);
          acc[1][g] = mf(a1, sf[ks][g], acc[1][g]);
        }
      }
#pragma unroll
      for (int rt = 0; rt < 2; ++rt)
#pragma unroll
        for (int r = 0; r < 4; ++r)
          storeH(h1w, rt * 16 + hi * 4 + r, colb + lo,
                 cellup(acc[rt][0][r], acc[rt][1][r], acc[rt][2][r], acc[rt][3][r], c1s[rt][r]));
    }
    __syncthreads();
    cur ^= 1;
  }
  // final states: h0(100) in h0B[cur^1], h1(100) in h1B[cur]
  int dc0 = cur ^ 1, dc1 = cur;

  // ================= restage for decoder =================
  {  // IMG_D -> wL
    const int4* src = (const int4*)(ws + WS_IMD);
    int4* dst = (int4*)wL;
    for (int i = tid; i < 6144; i += 512) dst[i] = src[i];
  }
  if (tid < 64) {  // dec_in = x[:, 99, :2]
    int r = tid >> 1, o = tid & 1;
    inpL[r * 2 + o] = x[(long long)(row0 + r) * 1600 + 1584 + o];
  }
  if (tid < 256) {
    int o = tid >> 7, k2 = tid & 127;
    *(unsigned short*)(fcwL + o * 256 + k2 * 2) = f2h(fcW[o * 128 + k2]);
  }
  // reload persistent frags for decoder: pwi = dWih1, pb3 = dWhh0 gate3
#pragma unroll
  for (int ks = 0; ks < 4; ++ks) {
#pragma unroll
    for (int g = 0; g < 4; ++g)
      pwi[ks][g] = *(const s16x8*)(ws + 2 * 131072 + ks * 32768 + g * 8192 + obase);
    pb3[ks] = *(const s16x8*)(ws + 5 * 131072 + ks * 32768 + obase3);
  }
  float dwx[4][2], b0f[4];
#pragma unroll
  for (int g = 0; g < 4; ++g) {
    int col = g * 128 + colb + lo;
    b0[g] = dbih0[col] + dbhh0[col];
    b1[g] = dbih1[col] + dbhh1[col];
    dwx[g][0] = dWih0[col * 2 + 0];
    dwx[g][1] = dWih0[col * 2 + 1];
  }
  float fb0 = fcb[0], fb1 = fcb[1];
#pragma unroll
  for (int g = 0; g < 4; ++g) b0f[g] = b0[g] + dwx[g][0] * fb0 + dwx[g][1] * fb1;
  __syncthreads();

  // ================= decoder =================
  // Phase A0 (t=0): h0^1 = cell0(inp0 [VALU], h0^0 @ dWhh0)
  {
    f32x4 acc[2][4];
    char* h0r = h0B + dc0 * 8192;
    char* h0w = h0B + (dc0 ^ 1) * 8192;
#pragma unroll
    for (int rt = 0; rt < 2; ++rt)
#pragma unroll
      for (int r = 0; r < 4; ++r) {
        float2 ip = *(const float2*)(inpL + (rt * 16 + hi * 4 + r) * 2);
#pragma unroll
        for (int g = 0; g < 4; ++g)
          acc[rt][g][r] = b0[g] + ip.x * dwx[g][0] + ip.y * dwx[g][1];
      }
#pragma unroll
    for (int ks = 0; ks < 4; ++ks) {
      s16x8 a0 = ldA(h0r, 0, ks, lo, hi), a1 = ldA(h0r, 1, ks, lo, hi);
#pragma unroll
      for (int g = 0; g < 3; ++g) {
        s16x8 bb = ldB(wL, g * 128 + colb, ks, lo, hi);
        acc[0][g] = mf(a0, bb, acc[0][g]);
        acc[1][g] = mf(a1, bb, acc[1][g]);
      }
      acc[0][3] = mf(a0, pb3[ks], acc[0][3]);
      acc[1][3] = mf(a1, pb3[ks], acc[1][3]);
    }
#pragma unroll
    for (int rt = 0; rt < 2; ++rt)
#pragma unroll
      for (int r = 0; r < 4; ++r)
        storeH(h0w, rt * 16 + hi * 4 + r, colb + lo,
               cellup(acc[rt][0][r], acc[rt][1][r], acc[rt][2][r], acc[rt][3][r], c0s[rt][r]));
    dc0 ^= 1;
    __syncthreads();
  }

  for (int t = 0; t < 60; ++t) {
    // ---- Phase B(t): h1^{t+1} = cell1(h0^{t+1} @ dWih1 + h1^t @ dWhh1)
    {
      char* h0r = h0B + dc0 * 8192;
      char* h1r = h1B + dc1 * 8192;
      char* h1w = h1B + (dc1 ^ 1) * 8192;
      // issue ALL streamed dWhh1 frags at top (land under persistent MFMAs)
      int lf = 0;
      asm("" : "+s"(lf));
      const char* WBh = ws + 3 * 131072 + lf;  // dWhh1 records
      s16x8 sf[4][4];
#pragma unroll
      for (int ks = 0; ks < 4; ++ks)
#pragma unroll
        for (int g = 0; g < 4; ++g)
          sf[ks][g] = *(const s16x8*)(WBh + ks * 32768 + g * 8192 + obase);
      f32x4 acc[2][4];
#pragma unroll
      for (int g = 0; g < 4; ++g) { acc[0][g] = splat4(b1[g]); acc[1][g] = splat4(b1[g]); }
      // persistent half: A = h0^{t+1}, B = pwi (dWih1)
#pragma unroll
      for (int ks = 0; ks < 4; ++ks) {
        s16x8 a0 = ldA(h0r, 0, ks, lo, hi), a1 = ldA(h0r, 1, ks, lo, hi);
#pragma unroll
        for (int g = 0; g < 4; ++g) {
          acc[0][g] = mf(a0, pwi[ks][g], acc[0][g]);
          acc[1][g] = mf(a1, pwi[ks][g], acc[1][g]);
        }
      }
      // streamed half: A = h1^t, B = sf
#pragma unroll
      for (int ks = 0; ks < 4; ++ks) {
        s16x8 a0 = ldA(h1r, 0, ks, lo, hi), a1 = ldA(h1r, 1, ks, lo, hi);
#pragma unroll
        for (int g = 0; g < 4; ++g) {
          acc[0][g] = mf(a0, sf[ks][g], acc[0][g]);
          acc[1][g] = mf(a1, sf[ks][g], acc[1][g]);
        }
      }
#pragma unroll
      for (int rt = 0; rt < 2; ++rt)
#pragma unroll
        for (int r = 0; r < 4; ++r)
          storeH(h1w, rt * 16 + hi * 4 + r, colb + lo,
                 cellup(acc[rt][0][r], acc[rt][1][r], acc[rt][2][r], acc[rt][3][r], c1s[rt][r]));
      dc1 ^= 1;
      __syncthreads();
    }

    // ---- Phase A(t+1): FC out(t) (all waves) then
    //      h0^{t+2} = cell0'(h1^{t+1} @ Wcomb + h0^{t+1} @ dWhh0)
    {
      char* h1r = h1B + dc1 * 8192;   // h1^{t+1}
      // issue ALL Wcomb frags at top (land under FC + LDS MFMAs)
      s16x8 cf[4][4];
      if (t < 59) {
        int lf = 0;
        asm("" : "+s"(lf));
        const char* WC = ws + 6 * 131072 + lf;   // Wcomb records
#pragma unroll
        for (int ks = 0; ks < 4; ++ks)
#pragma unroll
          for (int g = 0; g < 4; ++g)
            cf[ks][g] = *(const s16x8*)(WC + ks * 32768 + g * 8192 + obase);
      }
      {  // distributed FC: 64 sums (32 rows x 2 outs), 8 lanes x 2 slots each
        int rl = l >> 4, oo = (l >> 3) & 1, seg = l & 7;
        int row = w * 4 + rl;
        s16x8 hv0 = *(const s16x8*)(h1r + swz(row, seg));
        s16x8 wv0 = *(const s16x8*)(fcwL + oo * 256 + seg * 16);
        s16x8 hv1 = *(const s16x8*)(h1r + swz(row, seg + 8));
        s16x8 wv1 = *(const s16x8*)(fcwL + oo * 256 + (seg + 8) * 16);
        float sum = 0.f;
#pragma unroll
        for (int j = 0; j < 8; ++j)
          sum += h2f(hv0[j]) * h2f(wv0[j]) + h2f(hv1[j]) * h2f(wv1[j]);
        sum += __shfl_xor(sum, 1);
        sum += __shfl_xor(sum, 2);
        sum += __shfl_xor(sum, 4);
        if (seg == 0)
          out[((long long)(row0 + row) * 60 + t) * 2 + oo] = sum + (oo ? fb1 : fb0);
      }
      if (t < 59) {
        char* h0r = h0B + dc0 * 8192;
        char* h0w = h0B + (dc0 ^ 1) * 8192;
        f32x4 acc[2][4];
#pragma unroll
        for (int g = 0; g < 4; ++g) { acc[0][g] = splat4(b0f[g]); acc[1][g] = splat4(b0f[g]); }
        // LDS 3-gate + persistent gate-3 on h0r (covers cf latency)
#pragma unroll
        for (int ks = 0; ks < 4; ++ks) {
          s16x8 a0 = ldA(h0r, 0, ks, lo, hi), a1 = ldA(h0r, 1, ks, lo, hi);
#pragma unroll
          for (int g = 0; g < 3; ++g) {
            s16x8 bb = ldB(wL, g * 128 + colb, ks, lo, hi);
            acc[0][g] = mf(a0, bb, acc[0][g]);
            acc[1][g] = mf(a1, bb, acc[1][g]);
          }
          acc[0][3] = mf(a0, pb3[ks], acc[0][3]);
          acc[1][3] = mf(a1, pb3[ks], acc[1][3]);
        }
        // Wcomb half on h1^{t+1}
#pragma unroll
        for (int ks = 0; ks < 4; ++ks) {
          s16x8 e0 = ldA(h1r, 0, ks, lo, hi), e1 = ldA(h1r, 1, ks, lo, hi);
#pragma unroll
          for (int g = 0; g < 4; ++g) {
            acc[0][g] = mf(e0, cf[ks][g], acc[0][g]);
            acc[1][g] = mf(e1, cf[ks][g], acc[1][g]);
          }
        }
#pragma unroll
        for (int rt = 0; rt < 2; ++rt)
#pragma unroll
          for (int r = 0; r < 4; ++r)
            storeH(h0w, rt * 16 + hi * 4 + r, colb + lo,
                   cellup(acc[rt][0][r], acc[rt][1][r], acc[rt][2][r], acc[rt][3][r], c0s[rt][r]));
        dc0 ^= 1;
      }
      __syncthreads();
    }
  }
}

extern "C" void kernel_launch(void* const* d_in, const int* in_sizes, int n_in,
                              void* d_out, int out_size, void* d_ws, size_t ws_size,
                              hipStream_t stream) {
  (void)in_sizes; (void)n_in; (void)out_size; (void)ws_size;
  const float* x      = (const float*)d_in[0];
  // d_in[1] = target_len (60), hardcoded
  const float* eWih0  = (const float*)d_in[2];
  const float* eWhh0  = (const float*)d_in[3];
  const float* ebih0  = (const float*)d_in[4];
  const float* ebhh0  = (const float*)d_in[5];
  const float* eWih1  = (const float*)d_in[6];
  const float* eWhh1  = (const float*)d_in[7];
  const float* ebih1  = (const float*)d_in[8];
  const float* ebhh1  = (const float*)d_in[9];
  const float* dWih0  = (const float*)d_in[10];
  const float* dWhh0  = (const float*)d_in[11];
  const float* dbih0  = (const float*)d_in[12];
  const float* dbhh0  = (const float*)d_in[13];
  const float* dWih1  = (const float*)d_in[14];
  const float* dWhh1  = (const float*)d_in[15];
  const float* dbih1  = (const float*)d_in[16];
  const float* dbhh1  = (const float*)d_in[17];
  const float* fcW    = (const float*)d_in[18];
  const float* fcb    = (const float*)d_in[19];
  float* out          = (float*)d_out;
  char* ws            = (char*)d_ws;

  prep_kernel<<<280, 256, 0, stream>>>(eWih0, eWhh0, eWih1, eWhh1,
                                       dWih0, dWhh0, dWih1, dWhh1, fcW, ws);

  fused_kernel<<<256, 512, 0, stream>>>(
      x, ebih0, ebhh0, ebih1, ebhh1, dWih0, dbih0, dbhh0, dbih1, dbhh1,
      fcW, fcb, ws, out);
}

// Round 20
// 1854.851 us; speedup vs baseline: 1.1443x; 1.1443x over previous
//
#include <hip/hip_runtime.h>

// R18: R16 (1.05ms baseline) + persistent eWhh1 -> encoder loop touches ZERO
// L2 (all weights in registers or LDS). Register law from the R16/R17 ledger:
// demand <=240 fine, >=270 per-phase spill disaster. This design: pwi 64 +
// pwh 64 + pb3 16 + wx0 16 + acc 32 + c 16 + misc ~30 = ~238.
//  - Encoder L1: h0r@pwi(eWih1) + h1r@pwh(eWhh1), all-register B operands.
//  - Encoder L0: wx0 + wL(3-gate LDS) + pb3 — unchanged from R16.
//  - Decoder: pwi<-dWih1, pwh<-dWhh1, pb3<-dWhh0g3 (reload once); phase B
//    fully persistent; phase A keeps R16's 2-deep Wcomb juggle (wx0 dead).
// R17's mistake (issue-all-at-top, 64 live streamed regs -> ~290 demand ->
// 1.4GB/launch scratch writes) is reverted.

using s16x8 = __attribute__((ext_vector_type(8))) short;
using h16x8 = __attribute__((ext_vector_type(8))) _Float16;
using f32x4 = __attribute__((ext_vector_type(4))) float;

#define DEV static __device__ __forceinline__

DEV unsigned short f2h(float f) {
  _Float16 h = (_Float16)f;  // RNE
  return __builtin_bit_cast(unsigned short, h);
}
DEV float h2f(short h) {
  return (float)__builtin_bit_cast(_Float16, (unsigned short)h);
}
DEV float rcp_(float x) { return __builtin_amdgcn_rcpf(x); }
DEV float sigm(float v) { return rcp_(1.0f + __expf(-v)); }
DEV float tanh_(float v) {  // 1 - 2/(e^{2v}+1)
  float e = __expf(2.0f * v);
  return 1.0f - 2.0f * rcp_(e + 1.0f);
}
DEV f32x4 mf(s16x8 a, s16x8 b, f32x4 c) {
  return __builtin_amdgcn_mfma_f32_16x16x32_f16(
      __builtin_bit_cast(h16x8, a), __builtin_bit_cast(h16x8, b), c, 0, 0, 0);
}
DEV f32x4 splat4(float v) { f32x4 r = {v, v, v, v}; return r; }

// [rows][128] fp16 buffer; 16 slots of 8 fp16 per row, XOR-swizzled.
DEV int swz(int row, int slot) { return row * 256 + (((slot ^ row) & 15) << 4); }
DEV s16x8 ldA(const char* buf, int rt, int ks, int lo, int hi) {
  return *(const s16x8*)(buf + swz(rt * 16 + lo, ks * 4 + hi));
}
DEV s16x8 ldB(const char* wlds, int colbase, int ks, int lo, int hi) {
  return *(const s16x8*)(wlds + swz(colbase + lo, ks * 4 + hi));
}
DEV void storeH(char* buf, int row, int col, unsigned short v) {
  int addr = row * 256 + ((((col >> 3) ^ row) & 15) << 4) + (col & 7) * 2;
  *(unsigned short*)(buf + addr) = v;
}
DEV unsigned short cellup(float gi, float gf, float gg, float go, float& c) {
  float i = sigm(gi), f = sigm(gf), g2 = tanh_(gg), o = sigm(go);
  c = f * c + i * g2;
  return f2h(o * tanh_(c));
}

// ---- d_ws layout (bytes) ----
// frag records, mats m*131072, addr = m*131072 + ks*32768 + col*64 + hi*16
//   m: 0=eWih1 1=eWhh1 2=dWih1 3=dWhh1 4=eWhh0 5=dWhh0 6=Wcomb(dWih0@fcW)
// WX (eWih0 K=16 zero-pad-32 frags) @917504 (32KB)
// IMG_E (eWhh0 rows 0..383 swizzled) @950272 (96KB)
// IMG_D (dWhh0 rows 0..383 swizzled) @1048576 (96KB)
#define WS_WX  917504
#define WS_IME 950272
#define WS_IMD 1048576

__global__ void prep_kernel(
    const float* __restrict__ eWih0, const float* __restrict__ eWhh0,
    const float* __restrict__ eWih1, const float* __restrict__ eWhh1,
    const float* __restrict__ dWih0, const float* __restrict__ dWhh0,
    const float* __restrict__ dWih1, const float* __restrict__ dWhh1,
    const float* __restrict__ fcW, char* __restrict__ ws) {
  int idx = blockIdx.x * 256 + threadIdx.x;
  if (idx < 57344) {  // 7 mats x 8192 fragment records
    int m = idx >> 13, r = idx & 8191;
    int col = r >> 4, ks = (r >> 2) & 3, hi = r & 3;
    s16x8 v;
    if (m == 6) {  // Wcomb[col][k] = dWih0[col][0]*fcW[0][k]+dWih0[col][1]*fcW[1][k]
      float w0 = dWih0[col * 2 + 0], w1 = dWih0[col * 2 + 1];
#pragma unroll
      for (int j = 0; j < 8; ++j) {
        int k = ks * 32 + hi * 8 + j;
        v[j] = (short)f2h(w0 * fcW[k] + w1 * fcW[128 + k]);
      }
    } else {
      const float* W;
      switch (m) {
        case 0: W = eWih1; break;
        case 1: W = eWhh1; break;
        case 2: W = dWih1; break;
        case 3: W = dWhh1; break;
        case 4: W = eWhh0; break;
        default: W = dWhh0; break;
      }
      const float* p = W + col * 128 + ks * 32 + hi * 8;
#pragma unroll
      for (int j = 0; j < 8; ++j) v[j] = (short)f2h(p[j]);
    }
    *(s16x8*)(ws + m * 131072 + ks * 32768 + col * 64 + hi * 16) = v;
  } else if (idx < 59392) {  // WX frags
    int r3 = idx - 57344;
    int col = r3 >> 2, hi = r3 & 3;
    s16x8 v;
#pragma unroll
    for (int j = 0; j < 8; ++j) v[j] = 0;
    if (hi < 2) {
      const float* p = eWih0 + col * 16 + hi * 8;
#pragma unroll
      for (int j = 0; j < 8; ++j) v[j] = (short)f2h(p[j]);
    }
    *(s16x8*)(ws + WS_WX + col * 64 + hi * 16) = v;
  } else if (idx < 71680) {  // swizzled 3-gate images (rows 0..383)
    int r2 = idx - 59392;
    int m = (r2 >= 6144), rr = m ? r2 - 6144 : r2;
    int row = rr >> 4, s = rr & 15;
    const float* p = (m ? dWhh0 : eWhh0) + row * 128 + s * 8;
    s16x8 v;
#pragma unroll
    for (int j = 0; j < 8; ++j) v[j] = (short)f2h(p[j]);
    *(s16x8*)(ws + (m ? WS_IMD : WS_IME) + row * 256 + (((s ^ row) & 15) << 4)) = v;
  }
}

__global__ __launch_bounds__(512, 2) void fused_kernel(
    const float* __restrict__ x,
    const float* __restrict__ ebih0, const float* __restrict__ ebhh0,
    const float* __restrict__ ebih1, const float* __restrict__ ebhh1,
    const float* __restrict__ dWih0,
    const float* __restrict__ dbih0, const float* __restrict__ dbhh0,
    const float* __restrict__ dbih1, const float* __restrict__ dbhh1,
    const float* __restrict__ fcW, const float* __restrict__ fcb,
    const char* __restrict__ ws, float* __restrict__ out) {
  __shared__ __align__(16) char smem[136960];
  char* wL   = smem;                       // 98304: 3-gate W_hh0 image
  char* h0B  = smem + 98304;               // 2 x 8192
  char* h1B  = smem + 114688;              // 2 x 8192
  char* xB   = smem + 131072;              // 2 x 2560
  float* inpL = (float*)(smem + 136192);   // 32x2 fp32 (decoder t=0 input)
  char* fcwL = smem + 136448;              // 2x128 fp16

  const int tid = threadIdx.x;
  const int w = tid >> 6, l = tid & 63, lo = l & 15, hi = l >> 4;
  const int row0 = blockIdx.x * 32;
  const int colb = w * 16;
  const int obase = (colb + lo) * 64 + hi * 16;   // frag offset, gate 0
  const int obase3 = obase + 384 * 64;            // gate 3

  // ================= init =================
  {  // stage IMG_E -> wL
    const int4* src = (const int4*)(ws + WS_IME);
    int4* dst = (int4*)wL;
    for (int i = tid; i < 6144; i += 512) dst[i] = src[i];
  }
  {  // zero h0B,h1B,xB
    int4 z = make_int4(0, 0, 0, 0);
    int4* p = (int4*)h0B;
    for (int i = tid; i < 2368; i += 512) p[i] = z;
  }

  float b0[4], b1[4];
  s16x8 wx0[4];
#pragma unroll
  for (int g = 0; g < 4; ++g) {
    int col = g * 128 + colb + lo;
    b0[g] = ebih0[col] + ebhh0[col];
    b1[g] = ebih1[col] + ebhh1[col];
    wx0[g] = *(const s16x8*)(ws + WS_WX + g * 8192 + obase);
  }
  // persistent weight fragments (loaded ONCE; reloaded at decoder switch):
  //   pwi = eWih1, pwh = eWhh1, pb3 = eWhh0 gate-3
  s16x8 pwi[4][4], pwh[4][4], pb3[4];
#pragma unroll
  for (int ks = 0; ks < 4; ++ks) {
#pragma unroll
    for (int g = 0; g < 4; ++g) {
      pwi[ks][g] = *(const s16x8*)(ws + 0 * 131072 + ks * 32768 + g * 8192 + obase);
      pwh[ks][g] = *(const s16x8*)(ws + 1 * 131072 + ks * 32768 + g * 8192 + obase);
    }
    pb3[ks] = *(const s16x8*)(ws + 4 * 131072 + ks * 32768 + obase3);
  }

  float c0s[2][4], c1s[2][4];
#pragma unroll
  for (int rt = 0; rt < 2; ++rt)
#pragma unroll
    for (int r = 0; r < 4; ++r) { c0s[rt][r] = 0.f; c1s[rt][r] = 0.f; }

  const int xr = tid >> 4, xf = tid & 15;
  const float* xrow = x + (long long)(row0 + xr) * 1600 + xf;
  *(unsigned short*)(xB + xr * 80 + xf * 2) = f2h(xrow[0]);  // x_0
  float xv = xrow[16];  // x_1
  int cur = 0;
  __syncthreads();

  // ================= encoder: 101 fused phases, 1 barrier each ============
  // (encoder loop reads NO L2 except the x prefetch: all weights reg/LDS)
  for (int k = 0; k <= 100; ++k) {
    char* h0r = h0B + cur * 8192;
    char* h0w = h0B + (cur ^ 1) * 8192;
    char* h1r = h1B + cur * 8192;
    char* h1w = h1B + (cur ^ 1) * 8192;
    char* xc  = xB + cur * 2560;
    char* xn  = xB + (cur ^ 1) * 2560;

    float xv_stage = xv;                       // x_{k+1}
    if (k < 98) xv = xrow[(k + 2) * 16];       // issue prefetch early

    if (k > 0) {  // ---- layer 1: h1(k) = cell1(h0(k)@eWih1 + h1(k-1)@eWhh1)
      f32x4 acc[2][4];
#pragma unroll
      for (int g = 0; g < 4; ++g) { acc[0][g] = splat4(b1[g]); acc[1][g] = splat4(b1[g]); }
#pragma unroll
      for (int ks = 0; ks < 4; ++ks) {
        s16x8 a0 = ldA(h0r, 0, ks, lo, hi), a1 = ldA(h0r, 1, ks, lo, hi);
#pragma unroll
        for (int g = 0; g < 4; ++g) {
          acc[0][g] = mf(a0, pwi[ks][g], acc[0][g]);
          acc[1][g] = mf(a1, pwi[ks][g], acc[1][g]);
        }
      }
#pragma unroll
      for (int ks = 0; ks < 4; ++ks) {
        s16x8 a0 = ldA(h1r, 0, ks, lo, hi), a1 = ldA(h1r, 1, ks, lo, hi);
#pragma unroll
        for (int g = 0; g < 4; ++g) {
          acc[0][g] = mf(a0, pwh[ks][g], acc[0][g]);
          acc[1][g] = mf(a1, pwh[ks][g], acc[1][g]);
        }
      }
#pragma unroll
      for (int rt = 0; rt < 2; ++rt)
#pragma unroll
        for (int r = 0; r < 4; ++r)
          storeH(h1w, rt * 16 + hi * 4 + r, colb + lo,
                 cellup(acc[rt][0][r], acc[rt][1][r], acc[rt][2][r], acc[rt][3][r], c1s[rt][r]));
    }

    if (k < 100) {  // ---- layer 0: h0(k+1) = cell0(x_k, h0(k))
      f32x4 acc[2][4];
#pragma unroll
      for (int g = 0; g < 4; ++g) { acc[0][g] = splat4(b0[g]); acc[1][g] = splat4(b0[g]); }
      {
        s16x8 a0 = *(const s16x8*)(xc + lo * 80 + hi * 16);
        s16x8 a1 = *(const s16x8*)(xc + (16 + lo) * 80 + hi * 16);
#pragma unroll
        for (int g = 0; g < 4; ++g) {
          acc[0][g] = mf(a0, wx0[g], acc[0][g]);
          acc[1][g] = mf(a1, wx0[g], acc[1][g]);
        }
      }
#pragma unroll
      for (int ks = 0; ks < 4; ++ks) {
        s16x8 a0 = ldA(h0r, 0, ks, lo, hi), a1 = ldA(h0r, 1, ks, lo, hi);
#pragma unroll
        for (int g = 0; g < 3; ++g) {
          s16x8 bb = ldB(wL, g * 128 + colb, ks, lo, hi);
          acc[0][g] = mf(a0, bb, acc[0][g]);
          acc[1][g] = mf(a1, bb, acc[1][g]);
        }
        acc[0][3] = mf(a0, pb3[ks], acc[0][3]);
        acc[1][3] = mf(a1, pb3[ks], acc[1][3]);
      }
#pragma unroll
      for (int rt = 0; rt < 2; ++rt)
#pragma unroll
        for (int r = 0; r < 4; ++r)
          storeH(h0w, rt * 16 + hi * 4 + r, colb + lo,
                 cellup(acc[rt][0][r], acc[rt][1][r], acc[rt][2][r], acc[rt][3][r], c0s[rt][r]));
      if (k < 99)  // stage x_{k+1} for next phase
        *(unsigned short*)(xn + xr * 80 + xf * 2) = f2h(xv_stage);
    }
    __syncthreads();
    cur ^= 1;
  }
  // final states: h0(100) in h0B[cur^1], h1(100) in h1B[cur]
  int dc0 = cur ^ 1, dc1 = cur;

  // ================= restage for decoder =================
  {  // IMG_D -> wL
    const int4* src = (const int4*)(ws + WS_IMD);
    int4* dst = (int4*)wL;
    for (int i = tid; i < 6144; i += 512) dst[i] = src[i];
  }
  if (tid < 64) {  // dec_in = x[:, 99, :2]
    int r = tid >> 1, o = tid & 1;
    inpL[r * 2 + o] = x[(long long)(row0 + r) * 1600 + 1584 + o];
  }
  if (tid < 256) {
    int o = tid >> 7, k2 = tid & 127;
    *(unsigned short*)(fcwL + o * 256 + k2 * 2) = f2h(fcW[o * 128 + k2]);
  }
  // reload persistent frags: pwi = dWih1, pwh = dWhh1, pb3 = dWhh0 gate3
#pragma unroll
  for (int ks = 0; ks < 4; ++ks) {
#pragma unroll
    for (int g = 0; g < 4; ++g) {
      pwi[ks][g] = *(const s16x8*)(ws + 2 * 131072 + ks * 32768 + g * 8192 + obase);
      pwh[ks][g] = *(const s16x8*)(ws + 3 * 131072 + ks * 32768 + g * 8192 + obase);
    }
    pb3[ks] = *(const s16x8*)(ws + 5 * 131072 + ks * 32768 + obase3);
  }
  float dwx[4][2], b0f[4];
#pragma unroll
  for (int g = 0; g < 4; ++g) {
    int col = g * 128 + colb + lo;
    b0[g] = dbih0[col] + dbhh0[col];
    b1[g] = dbih1[col] + dbhh1[col];
    dwx[g][0] = dWih0[col * 2 + 0];
    dwx[g][1] = dWih0[col * 2 + 1];
  }
  float fb0 = fcb[0], fb1 = fcb[1];
#pragma unroll
  for (int g = 0; g < 4; ++g) b0f[g] = b0[g] + dwx[g][0] * fb0 + dwx[g][1] * fb1;
  __syncthreads();

  // ================= decoder =================
  // Phase A0 (t=0): h0^1 = cell0(inp0 [VALU], h0^0 @ dWhh0)
  {
    f32x4 acc[2][4];
    char* h0r = h0B + dc0 * 8192;
    char* h0w = h0B + (dc0 ^ 1) * 8192;
#pragma unroll
    for (int rt = 0; rt < 2; ++rt)
#pragma unroll
      for (int r = 0; r < 4; ++r) {
        float2 ip = *(const float2*)(inpL + (rt * 16 + hi * 4 + r) * 2);
#pragma unroll
        for (int g = 0; g < 4; ++g)
          acc[rt][g][r] = b0[g] + ip.x * dwx[g][0] + ip.y * dwx[g][1];
      }
#pragma unroll
    for (int ks = 0; ks < 4; ++ks) {
      s16x8 a0 = ldA(h0r, 0, ks, lo, hi), a1 = ldA(h0r, 1, ks, lo, hi);
#pragma unroll
      for (int g = 0; g < 3; ++g) {
        s16x8 bb = ldB(wL, g * 128 + colb, ks, lo, hi);
        acc[0][g] = mf(a0, bb, acc[0][g]);
        acc[1][g] = mf(a1, bb, acc[1][g]);
      }
      acc[0][3] = mf(a0, pb3[ks], acc[0][3]);
      acc[1][3] = mf(a1, pb3[ks], acc[1][3]);
    }
#pragma unroll
    for (int rt = 0; rt < 2; ++rt)
#pragma unroll
      for (int r = 0; r < 4; ++r)
        storeH(h0w, rt * 16 + hi * 4 + r, colb + lo,
               cellup(acc[rt][0][r], acc[rt][1][r], acc[rt][2][r], acc[rt][3][r], c0s[rt][r]));
    dc0 ^= 1;
    __syncthreads();
  }

  for (int t = 0; t < 60; ++t) {
    // ---- Phase B(t): h1^{t+1} = cell1(h0^{t+1} @ dWih1 + h1^t @ dWhh1)
    //      (fully persistent B operands)
    {
      char* h0r = h0B + dc0 * 8192;
      char* h1r = h1B + dc1 * 8192;
      char* h1w = h1B + (dc1 ^ 1) * 8192;
      f32x4 acc[2][4];
#pragma unroll
      for (int g = 0; g < 4; ++g) { acc[0][g] = splat4(b1[g]); acc[1][g] = splat4(b1[g]); }
#pragma unroll
      for (int ks = 0; ks < 4; ++ks) {
        s16x8 a0 = ldA(h0r, 0, ks, lo, hi), a1 = ldA(h0r, 1, ks, lo, hi);
#pragma unroll
        for (int g = 0; g < 4; ++g) {
          acc[0][g] = mf(a0, pwi[ks][g], acc[0][g]);
          acc[1][g] = mf(a1, pwi[ks][g], acc[1][g]);
        }
      }
#pragma unroll
      for (int ks = 0; ks < 4; ++ks) {
        s16x8 a0 = ldA(h1r, 0, ks, lo, hi), a1 = ldA(h1r, 1, ks, lo, hi);
#pragma unroll
        for (int g = 0; g < 4; ++g) {
          acc[0][g] = mf(a0, pwh[ks][g], acc[0][g]);
          acc[1][g] = mf(a1, pwh[ks][g], acc[1][g]);
        }
      }
#pragma unroll
      for (int rt = 0; rt < 2; ++rt)
#pragma unroll
        for (int r = 0; r < 4; ++r)
          storeH(h1w, rt * 16 + hi * 4 + r, colb + lo,
                 cellup(acc[rt][0][r], acc[rt][1][r], acc[rt][2][r], acc[rt][3][r], c1s[rt][r]));
      dc1 ^= 1;
      __syncthreads();
    }

    // ---- Phase A(t+1): FC out(t) (all waves) then
    //      h0^{t+2} = cell0'(h1^{t+1} @ Wcomb + h0^{t+1} @ dWhh0)
    {
      char* h1r = h1B + dc1 * 8192;   // h1^{t+1}
      {  // distributed FC: 64 sums (32 rows x 2 outs), 8 lanes x 2 slots each
        int rl = l >> 4, oo = (l >> 3) & 1, seg = l & 7;
        int row = w * 4 + rl;
        s16x8 hv0 = *(const s16x8*)(h1r + swz(row, seg));
        s16x8 wv0 = *(const s16x8*)(fcwL + oo * 256 + seg * 16);
        s16x8 hv1 = *(const s16x8*)(h1r + swz(row, seg + 8));
        s16x8 wv1 = *(const s16x8*)(fcwL + oo * 256 + (seg + 8) * 16);
        float sum = 0.f;
#pragma unroll
        for (int j = 0; j < 8; ++j)
          sum += h2f(hv0[j]) * h2f(wv0[j]) + h2f(hv1[j]) * h2f(wv1[j]);
        sum += __shfl_xor(sum, 1);
        sum += __shfl_xor(sum, 2);
        sum += __shfl_xor(sum, 4);
        if (seg == 0)
          out[((long long)(row0 + row) * 60 + t) * 2 + oo] = sum + (oo ? fb1 : fb0);
      }
      if (t < 59) {
        char* h0r = h0B + dc0 * 8192;
        char* h0w = h0B + (dc0 ^ 1) * 8192;
        f32x4 acc[2][4];
#pragma unroll
        for (int g = 0; g < 4; ++g) { acc[0][g] = splat4(b0f[g]); acc[1][g] = splat4(b0f[g]); }
        int lf = 0;
        asm("" : "+s"(lf));
        const char* WC = ws + 6 * 131072 + lf;   // Wcomb records (streamed)
        s16x8 cf0[4], cf1[4];
#pragma unroll
        for (int g = 0; g < 4; ++g) {
          cf0[g] = *(const s16x8*)(WC + 0 * 32768 + g * 8192 + obase);
          cf1[g] = *(const s16x8*)(WC + 1 * 32768 + g * 8192 + obase);
        }
#pragma unroll
        for (int ks = 0; ks < 4; ++ks) {
          s16x8* ccur = (ks & 1) ? cf1 : cf0;
          s16x8 tmp[4];
          if (ks < 2) {
            const char* wkn = WC + (ks + 2) * 32768 + obase;
#pragma unroll
            for (int g = 0; g < 4; ++g) tmp[g] = *(const s16x8*)(wkn + g * 8192);
          }
          s16x8 a0 = ldA(h0r, 0, ks, lo, hi), a1 = ldA(h0r, 1, ks, lo, hi);
          s16x8 e0 = ldA(h1r, 0, ks, lo, hi), e1 = ldA(h1r, 1, ks, lo, hi);
#pragma unroll
          for (int g = 0; g < 3; ++g) {
            s16x8 bb = ldB(wL, g * 128 + colb, ks, lo, hi);
            acc[0][g] = mf(a0, bb, acc[0][g]);
            acc[1][g] = mf(a1, bb, acc[1][g]);
          }
          acc[0][3] = mf(a0, pb3[ks], acc[0][3]);
          acc[1][3] = mf(a1, pb3[ks], acc[1][3]);
#pragma unroll
          for (int g = 0; g < 4; ++g) {
            acc[0][g] = mf(e0, ccur[g], acc[0][g]);
            acc[1][g] = mf(e1, ccur[g], acc[1][g]);
          }
          if (ks < 2) {
            s16x8* crel = (ks & 1) ? cf1 : cf0;
#pragma unroll
            for (int g = 0; g < 4; ++g) crel[g] = tmp[g];
          }
        }
#pragma unroll
        for (int rt = 0; rt < 2; ++rt)
#pragma unroll
          for (int r = 0; r < 4; ++r)
            storeH(h0w, rt * 16 + hi * 4 + r, colb + lo,
                   cellup(acc[rt][0][r], acc[rt][1][r], acc[rt][2][r], acc[rt][3][r], c0s[rt][r]));
        dc0 ^= 1;
      }
      __syncthreads();
    }
  }
}

extern "C" void kernel_launch(void* const* d_in, const int* in_sizes, int n_in,
                              void* d_out, int out_size, void* d_ws, size_t ws_size,
                              hipStream_t stream) {
  (void)in_sizes; (void)n_in; (void)out_size; (void)ws_size;
  const float* x      = (const float*)d_in[0];
  // d_in[1] = target_len (60), hardcoded
  const float* eWih0  = (const float*)d_in[2];
  const float* eWhh0  = (const float*)d_in[3];
  const float* ebih0  = (const float*)d_in[4];
  const float* ebhh0  = (const float*)d_in[5];
  const float* eWih1  = (const float*)d_in[6];
  const float* eWhh1  = (const float*)d_in[7];
  const float* ebih1  = (const float*)d_in[8];
  const float* ebhh1  = (const float*)d_in[9];
  const float* dWih0  = (const float*)d_in[10];
  const float* dWhh0  = (const float*)d_in[11];
  const float* dbih0  = (const float*)d_in[12];
  const float* dbhh0  = (const float*)d_in[13];
  const float* dWih1  = (const float*)d_in[14];
  const float* dWhh1  = (const float*)d_in[15];
  const float* dbih1  = (const float*)d_in[16];
  const float* dbhh1  = (const float*)d_in[17];
  const float* fcW    = (const float*)d_in[18];
  const float* fcb    = (const float*)d_in[19];
  float* out          = (float*)d_out;
  char* ws            = (char*)d_ws;

  prep_kernel<<<280, 256, 0, stream>>>(eWih0, eWhh0, eWih1, eWhh1,
                                       dWih0, dWhh0, dWih1, dWhh1, fcW, ws);

  fused_kernel<<<256, 512, 0, stream>>>(
      x, ebih0, ebhh0, ebih1, ebhh1, dWih0, dbih0, dbhh0, dbih1, dbhh1,
      fcW, fcb, ws, out);
}

// Round 21
// 1053.001 us; speedup vs baseline: 2.0157x; 1.7615x over previous
//
#include <hip/hip_runtime.h>

// R19 = R16 restored verbatim (the measured optimum: 1.05ms, absmax 4.88e-4).
// R17 (+64 in-flight regs) and R18 (+64 persistent regs) both violated the
// register law (total live frag-regs must stay <= ~96; >=128 -> per-phase
// scratch spill, 1.4GB/0.6GB writes, ~2x regression). R16's configuration:
//  - pwi[4][4] (64 reg) persistent: eWih1 (enc) / dWih1 (dec)
//  - pb3[4]    (16 reg) persistent: W_hh0 gate-3 (eWhh0 enc / dWhh0 dec)
//  - eWhh1/dWhh1 + Wcomb streamed with the 2-deep juggle
//  - W_hh0 gates i,f,g in LDS (96KB swizzled image)
//  - fused encoder phase (1 barrier), decoder FC-fold (2 barriers/step),
//    distributed FC, rcp-based activations, fp32 output.
// Structural plateau analysis: per-phase cost = cellup trans work (~2.6k
// cyc/SIMD, irreducible) + recurrence chain latency at 8 waves/CU (pinned
// by LDS-resident W_hh0, which R12 proved is cheaper than streaming it).

using s16x8 = __attribute__((ext_vector_type(8))) short;
using h16x8 = __attribute__((ext_vector_type(8))) _Float16;
using f32x4 = __attribute__((ext_vector_type(4))) float;

#define DEV static __device__ __forceinline__

DEV unsigned short f2h(float f) {
  _Float16 h = (_Float16)f;  // RNE
  return __builtin_bit_cast(unsigned short, h);
}
DEV float h2f(short h) {
  return (float)__builtin_bit_cast(_Float16, (unsigned short)h);
}
DEV float rcp_(float x) { return __builtin_amdgcn_rcpf(x); }
DEV float sigm(float v) { return rcp_(1.0f + __expf(-v)); }
DEV float tanh_(float v) {  // 1 - 2/(e^{2v}+1)
  float e = __expf(2.0f * v);
  return 1.0f - 2.0f * rcp_(e + 1.0f);
}
DEV f32x4 mf(s16x8 a, s16x8 b, f32x4 c) {
  return __builtin_amdgcn_mfma_f32_16x16x32_f16(
      __builtin_bit_cast(h16x8, a), __builtin_bit_cast(h16x8, b), c, 0, 0, 0);
}
DEV f32x4 splat4(float v) { f32x4 r = {v, v, v, v}; return r; }

// [rows][128] fp16 buffer; 16 slots of 8 fp16 per row, XOR-swizzled.
DEV int swz(int row, int slot) { return row * 256 + (((slot ^ row) & 15) << 4); }
DEV s16x8 ldA(const char* buf, int rt, int ks, int lo, int hi) {
  return *(const s16x8*)(buf + swz(rt * 16 + lo, ks * 4 + hi));
}
DEV s16x8 ldB(const char* wlds, int colbase, int ks, int lo, int hi) {
  return *(const s16x8*)(wlds + swz(colbase + lo, ks * 4 + hi));
}
DEV void storeH(char* buf, int row, int col, unsigned short v) {
  int addr = row * 256 + ((((col >> 3) ^ row) & 15) << 4) + (col & 7) * 2;
  *(unsigned short*)(buf + addr) = v;
}
DEV unsigned short cellup(float gi, float gf, float gg, float go, float& c) {
  float i = sigm(gi), f = sigm(gf), g2 = tanh_(gg), o = sigm(go);
  c = f * c + i * g2;
  return f2h(o * tanh_(c));
}

// ---- d_ws layout (bytes) ----
// frag records, mats m*131072, addr = m*131072 + ks*32768 + col*64 + hi*16
//   m: 0=eWih1 1=eWhh1 2=dWih1 3=dWhh1 4=eWhh0 5=dWhh0 6=Wcomb(dWih0@fcW)
// WX (eWih0 K=16 zero-pad-32 frags) @917504 (32KB)
// IMG_E (eWhh0 rows 0..383 swizzled) @950272 (96KB)
// IMG_D (dWhh0 rows 0..383 swizzled) @1048576 (96KB)
#define WS_WX  917504
#define WS_IME 950272
#define WS_IMD 1048576

__global__ void prep_kernel(
    const float* __restrict__ eWih0, const float* __restrict__ eWhh0,
    const float* __restrict__ eWih1, const float* __restrict__ eWhh1,
    const float* __restrict__ dWih0, const float* __restrict__ dWhh0,
    const float* __restrict__ dWih1, const float* __restrict__ dWhh1,
    const float* __restrict__ fcW, char* __restrict__ ws) {
  int idx = blockIdx.x * 256 + threadIdx.x;
  if (idx < 57344) {  // 7 mats x 8192 fragment records
    int m = idx >> 13, r = idx & 8191;
    int col = r >> 4, ks = (r >> 2) & 3, hi = r & 3;
    s16x8 v;
    if (m == 6) {  // Wcomb[col][k] = dWih0[col][0]*fcW[0][k]+dWih0[col][1]*fcW[1][k]
      float w0 = dWih0[col * 2 + 0], w1 = dWih0[col * 2 + 1];
#pragma unroll
      for (int j = 0; j < 8; ++j) {
        int k = ks * 32 + hi * 8 + j;
        v[j] = (short)f2h(w0 * fcW[k] + w1 * fcW[128 + k]);
      }
    } else {
      const float* W;
      switch (m) {
        case 0: W = eWih1; break;
        case 1: W = eWhh1; break;
        case 2: W = dWih1; break;
        case 3: W = dWhh1; break;
        case 4: W = eWhh0; break;
        default: W = dWhh0; break;
      }
      const float* p = W + col * 128 + ks * 32 + hi * 8;
#pragma unroll
      for (int j = 0; j < 8; ++j) v[j] = (short)f2h(p[j]);
    }
    *(s16x8*)(ws + m * 131072 + ks * 32768 + col * 64 + hi * 16) = v;
  } else if (idx < 59392) {  // WX frags
    int r3 = idx - 57344;
    int col = r3 >> 2, hi = r3 & 3;
    s16x8 v;
#pragma unroll
    for (int j = 0; j < 8; ++j) v[j] = 0;
    if (hi < 2) {
      const float* p = eWih0 + col * 16 + hi * 8;
#pragma unroll
      for (int j = 0; j < 8; ++j) v[j] = (short)f2h(p[j]);
    }
    *(s16x8*)(ws + WS_WX + col * 64 + hi * 16) = v;
  } else if (idx < 71680) {  // swizzled 3-gate images (rows 0..383)
    int r2 = idx - 59392;
    int m = (r2 >= 6144), rr = m ? r2 - 6144 : r2;
    int row = rr >> 4, s = rr & 15;
    const float* p = (m ? dWhh0 : eWhh0) + row * 128 + s * 8;
    s16x8 v;
#pragma unroll
    for (int j = 0; j < 8; ++j) v[j] = (short)f2h(p[j]);
    *(s16x8*)(ws + (m ? WS_IMD : WS_IME) + row * 256 + (((s ^ row) & 15) << 4)) = v;
  }
}

__global__ __launch_bounds__(512, 2) void fused_kernel(
    const float* __restrict__ x,
    const float* __restrict__ ebih0, const float* __restrict__ ebhh0,
    const float* __restrict__ ebih1, const float* __restrict__ ebhh1,
    const float* __restrict__ dWih0,
    const float* __restrict__ dbih0, const float* __restrict__ dbhh0,
    const float* __restrict__ dbih1, const float* __restrict__ dbhh1,
    const float* __restrict__ fcW, const float* __restrict__ fcb,
    const char* __restrict__ ws, float* __restrict__ out) {
  __shared__ __align__(16) char smem[136960];
  char* wL   = smem;                       // 98304: 3-gate W_hh0 image
  char* h0B  = smem + 98304;               // 2 x 8192
  char* h1B  = smem + 114688;              // 2 x 8192
  char* xB   = smem + 131072;              // 2 x 2560
  float* inpL = (float*)(smem + 136192);   // 32x2 fp32 (decoder t=0 input)
  char* fcwL = smem + 136448;              // 2x128 fp16

  const int tid = threadIdx.x;
  const int w = tid >> 6, l = tid & 63, lo = l & 15, hi = l >> 4;
  const int row0 = blockIdx.x * 32;
  const int colb = w * 16;
  const int obase = (colb + lo) * 64 + hi * 16;   // frag offset, gate 0
  const int obase3 = obase + 384 * 64;            // gate 3

  // ================= init =================
  {  // stage IMG_E -> wL
    const int4* src = (const int4*)(ws + WS_IME);
    int4* dst = (int4*)wL;
    for (int i = tid; i < 6144; i += 512) dst[i] = src[i];
  }
  {  // zero h0B,h1B,xB
    int4 z = make_int4(0, 0, 0, 0);
    int4* p = (int4*)h0B;
    for (int i = tid; i < 2368; i += 512) p[i] = z;
  }

  float b0[4], b1[4];
  s16x8 wx0[4];
#pragma unroll
  for (int g = 0; g < 4; ++g) {
    int col = g * 128 + colb + lo;
    b0[g] = ebih0[col] + ebhh0[col];
    b1[g] = ebih1[col] + ebhh1[col];
    wx0[g] = *(const s16x8*)(ws + WS_WX + g * 8192 + obase);
  }
  // persistent weight fragments (loaded ONCE; reloaded at decoder switch)
  s16x8 pwi[4][4], pb3[4];
#pragma unroll
  for (int ks = 0; ks < 4; ++ks) {
#pragma unroll
    for (int g = 0; g < 4; ++g)
      pwi[ks][g] = *(const s16x8*)(ws + /*eWih1*/ ks * 32768 + g * 8192 + obase);
    pb3[ks] = *(const s16x8*)(ws + 4 * 131072 + ks * 32768 + obase3);  // eWhh0 g3
  }

  float c0s[2][4], c1s[2][4];
#pragma unroll
  for (int rt = 0; rt < 2; ++rt)
#pragma unroll
    for (int r = 0; r < 4; ++r) { c0s[rt][r] = 0.f; c1s[rt][r] = 0.f; }

  const int xr = tid >> 4, xf = tid & 15;
  const float* xrow = x + (long long)(row0 + xr) * 1600 + xf;
  *(unsigned short*)(xB + xr * 80 + xf * 2) = f2h(xrow[0]);  // x_0
  float xv = xrow[16];  // x_1
  int cur = 0;
  __syncthreads();

  // ================= encoder: 101 fused phases, 1 barrier each ============
  for (int k = 0; k <= 100; ++k) {
    char* h0r = h0B + cur * 8192;
    char* h0w = h0B + (cur ^ 1) * 8192;
    char* h1r = h1B + cur * 8192;
    char* h1w = h1B + (cur ^ 1) * 8192;
    char* xc  = xB + cur * 2560;
    char* xn  = xB + (cur ^ 1) * 2560;

    float xv_stage = xv;                       // x_{k+1}
    if (k < 98) xv = xrow[(k + 2) * 16];       // issue prefetch early

    if (k > 0) {  // ---- layer 1: h1(k) = cell1(h0(k)@eWih1 + h1(k-1)@eWhh1)
      f32x4 acc[2][4];
#pragma unroll
      for (int g = 0; g < 4; ++g) { acc[0][g] = splat4(b1[g]); acc[1][g] = splat4(b1[g]); }
      int lf = 0;
      asm("" : "+s"(lf));  // defeat LICM
      const char* W1h = ws + 131072 + lf;  // eWhh1 records
      // prefetch streamed groups ks=0,1 (land under the persistent MFMAs)
      s16x8 bf0[4], bf1[4];
#pragma unroll
      for (int g = 0; g < 4; ++g) {
        bf0[g] = *(const s16x8*)(W1h + 0 * 32768 + g * 8192 + obase);
        bf1[g] = *(const s16x8*)(W1h + 1 * 32768 + g * 8192 + obase);
      }
      // persistent half: A = h0(k), B = pwi (eWih1)
#pragma unroll
      for (int ks = 0; ks < 4; ++ks) {
        s16x8 a0 = ldA(h0r, 0, ks, lo, hi), a1 = ldA(h0r, 1, ks, lo, hi);
#pragma unroll
        for (int g = 0; g < 4; ++g) {
          acc[0][g] = mf(a0, pwi[ks][g], acc[0][g]);
          acc[1][g] = mf(a1, pwi[ks][g], acc[1][g]);
        }
      }
      // streamed half: A = h1(k-1), B = eWhh1, 2-deep pipeline
#pragma unroll
      for (int ks = 0; ks < 4; ++ks) {
        s16x8* bcur = (ks & 1) ? bf1 : bf0;
        if (ks < 2) {
          const char* wkn = W1h + (ks + 2) * 32768 + obase;
          s16x8* brel = (ks & 1) ? bf1 : bf0;  // reload the buffer being freed
          s16x8 tmp[4];
#pragma unroll
          for (int g = 0; g < 4; ++g) tmp[g] = *(const s16x8*)(wkn + g * 8192);
          s16x8 a0 = ldA(h1r, 0, ks, lo, hi), a1 = ldA(h1r, 1, ks, lo, hi);
#pragma unroll
          for (int g = 0; g < 4; ++g) {
            acc[0][g] = mf(a0, bcur[g], acc[0][g]);
            acc[1][g] = mf(a1, bcur[g], acc[1][g]);
          }
#pragma unroll
          for (int g = 0; g < 4; ++g) brel[g] = tmp[g];
        } else {
          s16x8 a0 = ldA(h1r, 0, ks, lo, hi), a1 = ldA(h1r, 1, ks, lo, hi);
#pragma unroll
          for (int g = 0; g < 4; ++g) {
            acc[0][g] = mf(a0, bcur[g], acc[0][g]);
            acc[1][g] = mf(a1, bcur[g], acc[1][g]);
          }
        }
      }
#pragma unroll
      for (int rt = 0; rt < 2; ++rt)
#pragma unroll
        for (int r = 0; r < 4; ++r)
          storeH(h1w, rt * 16 + hi * 4 + r, colb + lo,
                 cellup(acc[rt][0][r], acc[rt][1][r], acc[rt][2][r], acc[rt][3][r], c1s[rt][r]));
    }

    if (k < 100) {  // ---- layer 0: h0(k+1) = cell0(x_k, h0(k))
      f32x4 acc[2][4];
#pragma unroll
      for (int g = 0; g < 4; ++g) { acc[0][g] = splat4(b0[g]); acc[1][g] = splat4(b0[g]); }
      {
        s16x8 a0 = *(const s16x8*)(xc + lo * 80 + hi * 16);
        s16x8 a1 = *(const s16x8*)(xc + (16 + lo) * 80 + hi * 16);
#pragma unroll
        for (int g = 0; g < 4; ++g) {
          acc[0][g] = mf(a0, wx0[g], acc[0][g]);
          acc[1][g] = mf(a1, wx0[g], acc[1][g]);
        }
      }
#pragma unroll
      for (int ks = 0; ks < 4; ++ks) {
        s16x8 a0 = ldA(h0r, 0, ks, lo, hi), a1 = ldA(h0r, 1, ks, lo, hi);
#pragma unroll
        for (int g = 0; g < 3; ++g) {
          s16x8 bb = ldB(wL, g * 128 + colb, ks, lo, hi);
          acc[0][g] = mf(a0, bb, acc[0][g]);
          acc[1][g] = mf(a1, bb, acc[1][g]);
        }
        acc[0][3] = mf(a0, pb3[ks], acc[0][3]);
        acc[1][3] = mf(a1, pb3[ks], acc[1][3]);
      }
#pragma unroll
      for (int rt = 0; rt < 2; ++rt)
#pragma unroll
        for (int r = 0; r < 4; ++r)
          storeH(h0w, rt * 16 + hi * 4 + r, colb + lo,
                 cellup(acc[rt][0][r], acc[rt][1][r], acc[rt][2][r], acc[rt][3][r], c0s[rt][r]));
      if (k < 99)  // stage x_{k+1} for next phase
        *(unsigned short*)(xn + xr * 80 + xf * 2) = f2h(xv_stage);
    }
    __syncthreads();
    cur ^= 1;
  }
  // final states: h0(100) in h0B[cur^1], h1(100) in h1B[cur]
  int dc0 = cur ^ 1, dc1 = cur;

  // ================= restage for decoder =================
  {  // IMG_D -> wL
    const int4* src = (const int4*)(ws + WS_IMD);
    int4* dst = (int4*)wL;
    for (int i = tid; i < 6144; i += 512) dst[i] = src[i];
  }
  if (tid < 64) {  // dec_in = x[:, 99, :2]
    int r = tid >> 1, o = tid & 1;
    inpL[r * 2 + o] = x[(long long)(row0 + r) * 1600 + 1584 + o];
  }
  if (tid < 256) {
    int o = tid >> 7, k2 = tid & 127;
    *(unsigned short*)(fcwL + o * 256 + k2 * 2) = f2h(fcW[o * 128 + k2]);
  }
  // reload persistent frags for decoder: pwi = dWih1, pb3 = dWhh0 gate3
#pragma unroll
  for (int ks = 0; ks < 4; ++ks) {
#pragma unroll
    for (int g = 0; g < 4; ++g)
      pwi[ks][g] = *(const s16x8*)(ws + 2 * 131072 + ks * 32768 + g * 8192 + obase);
    pb3[ks] = *(const s16x8*)(ws + 5 * 131072 + ks * 32768 + obase3);
  }
  float dwx[4][2], b0f[4];
#pragma unroll
  for (int g = 0; g < 4; ++g) {
    int col = g * 128 + colb + lo;
    b0[g] = dbih0[col] + dbhh0[col];
    b1[g] = dbih1[col] + dbhh1[col];
    dwx[g][0] = dWih0[col * 2 + 0];
    dwx[g][1] = dWih0[col * 2 + 1];
  }
  float fb0 = fcb[0], fb1 = fcb[1];
#pragma unroll
  for (int g = 0; g < 4; ++g) b0f[g] = b0[g] + dwx[g][0] * fb0 + dwx[g][1] * fb1;
  __syncthreads();

  // ================= decoder =================
  // Phase A0 (t=0): h0^1 = cell0(inp0 [VALU], h0^0 @ dWhh0)
  {
    f32x4 acc[2][4];
    char* h0r = h0B + dc0 * 8192;
    char* h0w = h0B + (dc0 ^ 1) * 8192;
#pragma unroll
    for (int rt = 0; rt < 2; ++rt)
#pragma unroll
      for (int r = 0; r < 4; ++r) {
        float2 ip = *(const float2*)(inpL + (rt * 16 + hi * 4 + r) * 2);
#pragma unroll
        for (int g = 0; g < 4; ++g)
          acc[rt][g][r] = b0[g] + ip.x * dwx[g][0] + ip.y * dwx[g][1];
      }
#pragma unroll
    for (int ks = 0; ks < 4; ++ks) {
      s16x8 a0 = ldA(h0r, 0, ks, lo, hi), a1 = ldA(h0r, 1, ks, lo, hi);
#pragma unroll
      for (int g = 0; g < 3; ++g) {
        s16x8 bb = ldB(wL, g * 128 + colb, ks, lo, hi);
        acc[0][g] = mf(a0, bb, acc[0][g]);
        acc[1][g] = mf(a1, bb, acc[1][g]);
      }
      acc[0][3] = mf(a0, pb3[ks], acc[0][3]);
      acc[1][3] = mf(a1, pb3[ks], acc[1][3]);
    }
#pragma unroll
    for (int rt = 0; rt < 2; ++rt)
#pragma unroll
      for (int r = 0; r < 4; ++r)
        storeH(h0w, rt * 16 + hi * 4 + r, colb + lo,
               cellup(acc[rt][0][r], acc[rt][1][r], acc[rt][2][r], acc[rt][3][r], c0s[rt][r]));
    dc0 ^= 1;
    __syncthreads();
  }

  for (int t = 0; t < 60; ++t) {
    // ---- Phase B(t): h1^{t+1} = cell1(h0^{t+1} @ dWih1 + h1^t @ dWhh1)
    {
      char* h0r = h0B + dc0 * 8192;
      char* h1r = h1B + dc1 * 8192;
      char* h1w = h1B + (dc1 ^ 1) * 8192;
      f32x4 acc[2][4];
#pragma unroll
      for (int g = 0; g < 4; ++g) { acc[0][g] = splat4(b1[g]); acc[1][g] = splat4(b1[g]); }
      int lf = 0;
      asm("" : "+s"(lf));
      const char* WBh = ws + 3 * 131072 + lf;  // dWhh1 records
      s16x8 bf0[4], bf1[4];
#pragma unroll
      for (int g = 0; g < 4; ++g) {
        bf0[g] = *(const s16x8*)(WBh + 0 * 32768 + g * 8192 + obase);
        bf1[g] = *(const s16x8*)(WBh + 1 * 32768 + g * 8192 + obase);
      }
      // persistent half: A = h0^{t+1}, B = pwi (dWih1)
#pragma unroll
      for (int ks = 0; ks < 4; ++ks) {
        s16x8 a0 = ldA(h0r, 0, ks, lo, hi), a1 = ldA(h0r, 1, ks, lo, hi);
#pragma unroll
        for (int g = 0; g < 4; ++g) {
          acc[0][g] = mf(a0, pwi[ks][g], acc[0][g]);
          acc[1][g] = mf(a1, pwi[ks][g], acc[1][g]);
        }
      }
      // streamed half: A = h1^t, B = dWhh1, 2-deep
#pragma unroll
      for (int ks = 0; ks < 4; ++ks) {
        s16x8* bcur = (ks & 1) ? bf1 : bf0;
        if (ks < 2) {
          const char* wkn = WBh + (ks + 2) * 32768 + obase;
          s16x8* brel = (ks & 1) ? bf1 : bf0;
          s16x8 tmp[4];
#pragma unroll
          for (int g = 0; g < 4; ++g) tmp[g] = *(const s16x8*)(wkn + g * 8192);
          s16x8 a0 = ldA(h1r, 0, ks, lo, hi), a1 = ldA(h1r, 1, ks, lo, hi);
#pragma unroll
          for (int g = 0; g < 4; ++g) {
            acc[0][g] = mf(a0, bcur[g], acc[0][g]);
            acc[1][g] = mf(a1, bcur[g], acc[1][g]);
          }
#pragma unroll
          for (int g = 0; g < 4; ++g) brel[g] = tmp[g];
        } else {
          s16x8 a0 = ldA(h1r, 0, ks, lo, hi), a1 = ldA(h1r, 1, ks, lo, hi);
#pragma unroll
          for (int g = 0; g < 4; ++g) {
            acc[0][g] = mf(a0, bcur[g], acc[0][g]);
            acc[1][g] = mf(a1, bcur[g], acc[1][g]);
          }
        }
      }
#pragma unroll
      for (int rt = 0; rt < 2; ++rt)
#pragma unroll
        for (int r = 0; r < 4; ++r)
          storeH(h1w, rt * 16 + hi * 4 + r, colb + lo,
                 cellup(acc[rt][0][r], acc[rt][1][r], acc[rt][2][r], acc[rt][3][r], c1s[rt][r]));
      dc1 ^= 1;
      __syncthreads();
    }

    // ---- Phase A(t+1): FC out(t) (all waves) then
    //      h0^{t+2} = cell0'(h1^{t+1} @ Wcomb + h0^{t+1} @ dWhh0)
    {
      char* h1r = h1B + dc1 * 8192;   // h1^{t+1}
      {  // distributed FC: 64 sums (32 rows x 2 outs), 8 lanes x 2 slots each
        int rl = l >> 4, oo = (l >> 3) & 1, seg = l & 7;
        int row = w * 4 + rl;
        s16x8 hv0 = *(const s16x8*)(h1r + swz(row, seg));
        s16x8 wv0 = *(const s16x8*)(fcwL + oo * 256 + seg * 16);
        s16x8 hv1 = *(const s16x8*)(h1r + swz(row, seg + 8));
        s16x8 wv1 = *(const s16x8*)(fcwL + oo * 256 + (seg + 8) * 16);
        float sum = 0.f;
#pragma unroll
        for (int j = 0; j < 8; ++j)
          sum += h2f(hv0[j]) * h2f(wv0[j]) + h2f(hv1[j]) * h2f(wv1[j]);
        sum += __shfl_xor(sum, 1);
        sum += __shfl_xor(sum, 2);
        sum += __shfl_xor(sum, 4);
        if (seg == 0)
          out[((long long)(row0 + row) * 60 + t) * 2 + oo] = sum + (oo ? fb1 : fb0);
      }
      if (t < 59) {
        char* h0r = h0B + dc0 * 8192;
        char* h0w = h0B + (dc0 ^ 1) * 8192;
        f32x4 acc[2][4];
#pragma unroll
        for (int g = 0; g < 4; ++g) { acc[0][g] = splat4(b0f[g]); acc[1][g] = splat4(b0f[g]); }
        int lf = 0;
        asm("" : "+s"(lf));
        const char* WC = ws + 6 * 131072 + lf;   // Wcomb records
        s16x8 cf0[4], cf1[4];
#pragma unroll
        for (int g = 0; g < 4; ++g) {
          cf0[g] = *(const s16x8*)(WC + 0 * 32768 + g * 8192 + obase);
          cf1[g] = *(const s16x8*)(WC + 1 * 32768 + g * 8192 + obase);
        }
#pragma unroll
        for (int ks = 0; ks < 4; ++ks) {
          s16x8* ccur = (ks & 1) ? cf1 : cf0;
          s16x8 tmp[4];
          if (ks < 2) {
            const char* wkn = WC + (ks + 2) * 32768 + obase;
#pragma unroll
            for (int g = 0; g < 4; ++g) tmp[g] = *(const s16x8*)(wkn + g * 8192);
          }
          s16x8 a0 = ldA(h0r, 0, ks, lo, hi), a1 = ldA(h0r, 1, ks, lo, hi);
          s16x8 e0 = ldA(h1r, 0, ks, lo, hi), e1 = ldA(h1r, 1, ks, lo, hi);
#pragma unroll
          for (int g = 0; g < 3; ++g) {
            s16x8 bb = ldB(wL, g * 128 + colb, ks, lo, hi);
            acc[0][g] = mf(a0, bb, acc[0][g]);
            acc[1][g] = mf(a1, bb, acc[1][g]);
          }
          acc[0][3] = mf(a0, pb3[ks], acc[0][3]);
          acc[1][3] = mf(a1, pb3[ks], acc[1][3]);
#pragma unroll
          for (int g = 0; g < 4; ++g) {
            acc[0][g] = mf(e0, ccur[g], acc[0][g]);
            acc[1][g] = mf(e1, ccur[g], acc[1][g]);
          }
          if (ks < 2) {
            s16x8* crel = (ks & 1) ? cf1 : cf0;
#pragma unroll
            for (int g = 0; g < 4; ++g) crel[g] = tmp[g];
          }
        }
#pragma unroll
        for (int rt = 0; rt < 2; ++rt)
#pragma unroll
          for (int r = 0; r < 4; ++r)
            storeH(h0w, rt * 16 + hi * 4 + r, colb + lo,
                   cellup(acc[rt][0][r], acc[rt][1][r], acc[rt][2][r], acc[rt][3][r], c0s[rt][r]));
        dc0 ^= 1;
      }
      __syncthreads();
    }
  }
}

extern "C" void kernel_launch(void* const* d_in, const int* in_sizes, int n_in,
                              void* d_out, int out_size, void* d_ws, size_t ws_size,
                              hipStream_t stream) {
  (void)in_sizes; (void)n_in; (void)out_size; (void)ws_size;
  const float* x      = (const float*)d_in[0];
  // d_in[1] = target_len (60), hardcoded
  const float* eWih0  = (const float*)d_in[2];
  const float* eWhh0  = (const float*)d_in[3];
  const float* ebih0  = (const float*)d_in[4];
  const float* ebhh0  = (const float*)d_in[5];
  const float* eWih1  = (const float*)d_in[6];
  const float* eWhh1  = (const float*)d_in[7];
  const float* ebih1  = (const float*)d_in[8];
  const float* ebhh1  = (const float*)d_in[9];
  const float* dWih0  = (const float*)d_in[10];
  const float* dWhh0  = (const float*)d_in[11];
  const float* dbih0  = (const float*)d_in[12];
  const float* dbhh0  = (const float*)d_in[13];
  const float* dWih1  = (const float*)d_in[14];
  const float* dWhh1  = (const float*)d_in[15];
  const float* dbih1  = (const float*)d_in[16];
  const float* dbhh1  = (const float*)d_in[17];
  const float* fcW    = (const float*)d_in[18];
  const float* fcb    = (const float*)d_in[19];
  float* out          = (float*)d_out;
  char* ws            = (char*)d_ws;

  prep_kernel<<<280, 256, 0, stream>>>(eWih0, eWhh0, eWih1, eWhh1,
                                       dWih0, dWhh0, dWih1, dWhh1, fcW, ws);

  fused_kernel<<<256, 512, 0, stream>>>(
      x, ebih0, ebhh0, ebih1, ebhh1, dWih0, dbih0, dbhh0, dbih1, dbhh1,
      fcW, fcb, ws, out);
}